// Round 1
// baseline (308.223 us; speedup 1.0000x reference)
//
#include <hip/hip_runtime.h>

// Problem constants (from reference): T=1024, B=256, H=20
#define T_N 1024
#define B_N 256
#define H_N 20

// ---------------------------------------------------------------------------
// Kernel 1: me[i] = sigmoid( tanh(tanh(tanh(t_i*w1+b1)@w2+b2)@w3+b3) @ w4 + b4 )
// 1024 threads total (4 blocks x 256). Weights staged in LDS (broadcast reads).
// ---------------------------------------------------------------------------
__global__ __launch_bounds__(256) void me_kernel(
    const float* __restrict__ t,
    const float* __restrict__ w1, const float* __restrict__ b1,
    const float* __restrict__ w2, const float* __restrict__ b2,
    const float* __restrict__ w3, const float* __restrict__ b3,
    const float* __restrict__ w4, const float* __restrict__ b4,
    float* __restrict__ me_out)
{
    __shared__ float sW2[H_N * H_N];
    __shared__ float sW3[H_N * H_N];
    __shared__ float sW1[H_N], sB1[H_N], sB2[H_N], sB3[H_N], sW4[H_N];
    __shared__ float sB4;

    const int tid = threadIdx.x;
    for (int i = tid; i < H_N * H_N; i += 256) {
        sW2[i] = w2[i];
        sW3[i] = w3[i];
    }
    if (tid < H_N) {
        sW1[tid] = w1[tid];
        sB1[tid] = b1[tid];
        sB2[tid] = b2[tid];
        sB3[tid] = b3[tid];
        sW4[tid] = w4[tid];
    }
    if (tid == 0) sB4 = b4[0];
    __syncthreads();

    const int i = blockIdx.x * 256 + tid;
    if (i >= T_N) return;

    const float x = t[i];

    float h1[H_N], h2[H_N];
#pragma unroll
    for (int k = 0; k < H_N; ++k) h1[k] = tanhf(x * sW1[k] + sB1[k]);

#pragma unroll 4
    for (int k = 0; k < H_N; ++k) {
        float a = sB2[k];
#pragma unroll
        for (int j = 0; j < H_N; ++j) a += h1[j] * sW2[j * H_N + k];
        h2[k] = tanhf(a);
    }

    float a4 = sB4;
#pragma unroll 4
    for (int k = 0; k < H_N; ++k) {
        float a = sB3[k];
#pragma unroll
        for (int j = 0; j < H_N; ++j) a += h2[j] * sW3[j * H_N + k];
        a4 += tanhf(a) * sW4[k];
    }

    me_out[i] = 1.0f / (1.0f + expf(-a4));
}

// ---------------------------------------------------------------------------
// Kernel 2: the sequential scan. One wave (64 lanes) per batch element.
//
// integ_j = dt * sum_{t<j} me[T-j+t] * Ihist[t]   (Toeplitz matvec with
// feedback: Ihist[j] depends on integ_j). Chunked: lane L of chunk c owns the
// accumulator for step j = 64c + L. Pre-chunk: parallel dot over t < 64c.
// Within-chunk: one readlane broadcast + one predicated FMA per step.
// ---------------------------------------------------------------------------
__device__ __forceinline__ float bcast_lane(float v, int lane) {
    return __uint_as_float((unsigned)__builtin_amdgcn_readlane((int)__float_as_uint(v), lane));
}

__global__ __launch_bounds__(64) void scan_kernel(
    const float* __restrict__ t,
    const float* __restrict__ y,
    const float* __restrict__ beta_p,
    const float* __restrict__ gamma_p,
    const float* __restrict__ me,
    float* __restrict__ out)     // [solution (T*B*3) | diff (T*B*3)]
{
    __shared__ __align__(16) float sMe[T_N];
    __shared__ __align__(16) float sI[T_N];

    const int b = blockIdx.x;
    const int L = threadIdx.x;   // lane (single wave per block)

    for (int i = L; i < T_N; i += 64) sMe[i] = me[i];

    const float dt    = t[0] - t[1];
    const float beta  = beta_p[0];
    const float gamma = gamma_p[0];

    float S = y[b * 3 + 0];
    float I = y[b * 3 + 1];
    float R = y[b * 3 + 2];

    if (L == 0) sI[0] = I;

    float* __restrict__ diff = out + (size_t)T_N * B_N * 3;
    // diff[T-1] = 0
    if (L < 3) diff[((size_t)(T_N - 1) * B_N + b) * 3 + L] = 0.0f;

    // Per-lane captured outputs: lane L of chunk c stores sol[64c+L], diff[64c+L-1].
    // Chunk 0 lane 0: sol[0] = y0 (initial values below), no diff row.
    float oS = S, oI = I, oR = R, od0 = 0.0f, od1 = 0.0f, od2 = 0.0f;

    for (int c = 0; c < T_N / 64; ++c) {
        const int J = c * 64;

        // --- pre-chunk: acc = sum_{t=0}^{J-1} me[T - (J+L) + t] * Ihist[t] ---
        float acc = 0.0f;
        if (c == 0) {
            // t = 0 term (Ihist[0] = I0, produced by the initial condition)
            if (L > 0) acc = sMe[T_N - L] * I;   // I still == I0 here
        } else {
            const int base = T_N - J - L;
            for (int tt = 0; tt < J; tt += 4) {
                const float4 iv = *reinterpret_cast<const float4*>(&sI[tt]);
                float a0 = sMe[base + tt + 0] * iv.x;
                float a1 = sMe[base + tt + 1] * iv.y;
                float a2 = sMe[base + tt + 2] * iv.z;
                float a3 = sMe[base + tt + 3] * iv.w;
                acc += (a0 + a1) + (a2 + a3);
            }
        }

        // --- within-chunk serial steps: j = J + m ---
        const int m0 = (c == 0) ? 1 : 0;
        for (int m = m0; m < 64; ++m) {
            const float sum   = bcast_lane(acc, m);   // lane m's acc is complete
            const float integ = dt * sum;
            const float bSI   = beta * S * I;
            const float gI    = gamma * I;
            const float d0    = integ - bSI;
            const float d1    = bSI - gI;
            const float d2    = gI - integ;
            S += d0 * dt;
            I += d1 * dt;
            R += d2 * dt;
            if (L == m) {                 // owner lane captures step outputs
                oS = S; oI = I; oR = R;
                od0 = d0; od1 = d1; od2 = d2;
                sI[J + m] = I;            // publish Ihist[j] for future chunks
            }
            if (L > m) {                  // fold new Ihist[J+m] into future accs
                acc += sMe[T_N - L + m] * I;
            }
        }

        // --- chunk epilogue: write captured rows ---
        const int j = J + L;
        const size_t so = ((size_t)j * B_N + b) * 3;
        out[so + 0] = oS;
        out[so + 1] = oI;
        out[so + 2] = oR;
        if (j > 0) {
            const size_t dofs = ((size_t)(j - 1) * B_N + b) * 3;
            diff[dofs + 0] = od0;
            diff[dofs + 1] = od1;
            diff[dofs + 2] = od2;
        }
    }
}

// ---------------------------------------------------------------------------
// Launcher
// ---------------------------------------------------------------------------
extern "C" void kernel_launch(void* const* d_in, const int* in_sizes, int n_in,
                              void* d_out, int out_size, void* d_ws, size_t ws_size,
                              hipStream_t stream) {
    const float* t     = (const float*)d_in[0];
    const float* y     = (const float*)d_in[1];
    const float* w1    = (const float*)d_in[2];
    const float* b1    = (const float*)d_in[3];
    const float* w2    = (const float*)d_in[4];
    const float* b2    = (const float*)d_in[5];
    const float* w3    = (const float*)d_in[6];
    const float* b3    = (const float*)d_in[7];
    const float* w4    = (const float*)d_in[8];
    const float* b4    = (const float*)d_in[9];
    const float* beta  = (const float*)d_in[10];
    const float* gamma = (const float*)d_in[11];

    float* me  = (float*)d_ws;    // 1024 floats of scratch
    float* out = (float*)d_out;

    me_kernel<<<T_N / 256, 256, 0, stream>>>(t, w1, b1, w2, b2, w3, b3, w4, b4, me);
    scan_kernel<<<B_N, 64, 0, stream>>>(t, y, beta, gamma, me, out);
}

// Round 2
// 162.239 us; speedup vs baseline: 1.8998x; 1.8998x over previous
//
#include <hip/hip_runtime.h>

// Problem constants: T=1024, B=256, H=20
#define T_N 1024
#define B_N 256
#define H_N 20
#define SRW (T_N + 65)   // shifted-me row stride: 1089 ≡ 1 (mod 32) → bank-decorrelated

// ---------------------------------------------------------------------------
// Kernel 1: me[i] = sigmoid(tanh(tanh(tanh(t_i*w1+b1)@w2+b2)@w3+b3)@w4+b4)
// ---------------------------------------------------------------------------
__global__ __launch_bounds__(256) void me_kernel(
    const float* __restrict__ t,
    const float* __restrict__ w1, const float* __restrict__ b1,
    const float* __restrict__ w2, const float* __restrict__ b2,
    const float* __restrict__ w3, const float* __restrict__ b3,
    const float* __restrict__ w4, const float* __restrict__ b4,
    float* __restrict__ me_out)
{
    __shared__ float sW2[H_N * H_N];
    __shared__ float sW3[H_N * H_N];
    __shared__ float sW1[H_N], sB1[H_N], sB2[H_N], sB3[H_N], sW4[H_N];
    __shared__ float sB4;

    const int tid = threadIdx.x;
    for (int i = tid; i < H_N * H_N; i += 256) {
        sW2[i] = w2[i];
        sW3[i] = w3[i];
    }
    if (tid < H_N) {
        sW1[tid] = w1[tid];
        sB1[tid] = b1[tid];
        sB2[tid] = b2[tid];
        sB3[tid] = b3[tid];
        sW4[tid] = w4[tid];
    }
    if (tid == 0) sB4 = b4[0];
    __syncthreads();

    const int i = blockIdx.x * 256 + tid;
    if (i >= T_N) return;

    const float x = t[i];

    float h1[H_N], h2[H_N];
#pragma unroll
    for (int k = 0; k < H_N; ++k) h1[k] = tanhf(x * sW1[k] + sB1[k]);

#pragma unroll 4
    for (int k = 0; k < H_N; ++k) {
        float a = sB2[k];
#pragma unroll
        for (int j = 0; j < H_N; ++j) a += h1[j] * sW2[j * H_N + k];
        h2[k] = tanhf(a);
    }

    float a4 = sB4;
#pragma unroll 4
    for (int k = 0; k < H_N; ++k) {
        float a = sB3[k];
#pragma unroll
        for (int j = 0; j < H_N; ++j) a += h2[j] * sW3[j * H_N + k];
        a4 += tanhf(a) * sW4[k];
    }

    me_out[i] = 1.0f / (1.0f + expf(-a4));
}

// ---------------------------------------------------------------------------
// Kernel 2: producer/consumer scan. 256 threads/block = 4 waves, 1 batch/block.
//   wave 0 : serial SIR steps, LDS-free inner loop (register me tables),
//            also folds next-chunk contributions (acc_nxt).
//   waves 1-3 : history dot for chunk c+1 over t < 64c, float4 both operands,
//               double-buffered partials, 1 barrier per chunk.
// ---------------------------------------------------------------------------
__device__ __forceinline__ float rdlane(float v, int lane) {
    return __uint_as_float((unsigned)__builtin_amdgcn_readlane((int)__float_as_uint(v), lane));
}
__device__ __forceinline__ float comp(const float4& v, const int i) {
    return i == 0 ? v.x : i == 1 ? v.y : i == 2 ? v.z : v.w;
}

__global__ __launch_bounds__(256, 1) void scan_kernel(
    const float* __restrict__ t,
    const float* __restrict__ y,
    const float* __restrict__ beta_p,
    const float* __restrict__ gamma_p,
    const float* __restrict__ me,
    float* __restrict__ out)     // [solution (T*B*3) | diff (T*B*3)]
{
    // sR[r][x] = me[x + r] (0 beyond T) — 4 shifted copies so any alignment
    // class gets aligned float4 reads; stride 1089 decorrelates banks.
    __shared__ __align__(16) float sR[4 * SRW];
    __shared__ __align__(16) float sI[T_N];
    __shared__ float P[2][3][64];   // double-buffered per-dot-wave partials

    const int b   = blockIdx.x;
    const int tid = threadIdx.x;
    const int wid = tid >> 6;
    const int L   = tid & 63;

    for (int idx = tid; idx < 4 * SRW; idx += 256) {
        const int r  = idx / SRW;
        const int x  = idx - r * SRW;
        const int mi = x + r;
        sR[idx] = (mi < T_N) ? me[mi] : 0.0f;
    }

    const float dt  = t[0] - t[1];
    const float bta = beta_p[0];
    const float gma = gamma_p[0];

    float S = y[b * 3 + 0];
    float I = y[b * 3 + 1];
    float R = y[b * 3 + 2];

    if (tid == 0) sI[0] = I;

    float* __restrict__ diff = out + (size_t)T_N * B_N * 3;
    if (tid < 3) diff[((size_t)(T_N - 1) * B_N + b) * 3 + tid] = 0.0f;

    __syncthreads();   // sR, sI[0] visible

    // wave-0 persistent state (dead registers for dot waves)
    float4 rm4[16], rn4[16];
    float acc_cur = 0.0f, acc_nxt = 0.0f;
    float oS = S, oI = I, oR = R, od0 = 0.0f, od1 = 0.0f, od2 = 0.0f;

    if (wid == 0) {
        // rm[m]  = me_padded[T - L + m]      (0 for m >= L → unconditional fold)
        // rn[m]  = me[T - 64 - L + m]        (next-chunk weights, always valid)
        const int b0 = T_N - L;
        const int r0 = b0 & 3;
        const float* p0 = &sR[r0 * SRW + (b0 - r0)];
        const int b2 = T_N - 64 - L;
        const int r2 = b2 & 3;
        const float* p2 = &sR[r2 * SRW + (b2 - r2)];
#pragma unroll
        for (int k = 0; k < 16; ++k) {
            rm4[k] = *(const float4*)&p0[4 * k];
            rn4[k] = *(const float4*)&p2[4 * k];
        }
    }

#define SIR_STEP(m_)                                                      \
    {                                                                     \
        const float integ = dt * rdlane(acc_cur, (m_));                   \
        const float bSI = bta * S * I;                                    \
        const float gI  = gma * I;                                        \
        const float d0  = integ - bSI;                                    \
        const float d1  = bSI - gI;                                       \
        const float d2  = gI - integ;                                     \
        S += d0 * dt;                                                     \
        I += d1 * dt;                                                     \
        R += d2 * dt;                                                     \
        const bool cap = (L == (m_));                                     \
        oS  = cap ? S  : oS;                                              \
        oI  = cap ? I  : oI;                                              \
        oR  = cap ? R  : oR;                                              \
        od0 = cap ? d0 : od0;                                             \
        od1 = cap ? d1 : od1;                                             \
        od2 = cap ? d2 : od2;                                             \
        acc_cur = fmaf(comp(rm4[(m_) >> 2], (m_) & 3), I, acc_cur);       \
        acc_nxt = fmaf(comp(rn4[(m_) >> 2], (m_) & 3), I, acc_nxt);      \
    }

    for (int c = 0; c < 16; ++c) {
        if (wid == 0) {
            if (c == 0) {
                // pseudo-step m=0: fold initial I0 (lane 0's rm[0] = 0 pad)
                acc_cur = comp(rm4[0], 0) * I;
                acc_nxt = comp(rn4[0], 0) * I;
#pragma unroll
                for (int m = 1; m < 64; ++m) SIR_STEP(m)
            } else {
                acc_cur = acc_nxt + P[c & 1][0][L] + P[c & 1][1][L] + P[c & 1][2][L];
                acc_nxt = 0.0f;
#pragma unroll
                for (int m = 0; m < 64; ++m) SIR_STEP(m)
            }
            // chunk epilogue: publish I history, write captured rows
            const int j = 64 * c + L;
            sI[j] = oI;
            const size_t so = ((size_t)j * B_N + b) * 3;
            out[so + 0] = oS;
            out[so + 1] = oI;
            out[so + 2] = oR;
            if (j > 0) {
                const size_t dofs = ((size_t)(j - 1) * B_N + b) * 3;
                diff[dofs + 0] = od0;
                diff[dofs + 1] = od1;
                diff[dofs + 2] = od2;
            }
        } else if (c < 15) {
            // history dot for chunk c+1: t < 64c, strided 3-way across waves
            const int w  = wid - 1;
            const int bc = T_N - 64 * (c + 1) - L;
            const int rc = bc & 3;
            const float* mp = &sR[rc * SRW + (bc - rc)];
            float p = 0.0f;
            for (int q = w; q < 16 * c; q += 3) {
                const int tt = 4 * q;
                const float4 iv = *(const float4*)&sI[tt];
                const float4 mv = *(const float4*)&mp[tt];
                p += (iv.x * mv.x + iv.y * mv.y) + (iv.z * mv.z + iv.w * mv.w);
            }
            P[(c + 1) & 1][w][L] = p;
        }
        __syncthreads();
    }
#undef SIR_STEP
}

// ---------------------------------------------------------------------------
// Launcher
// ---------------------------------------------------------------------------
extern "C" void kernel_launch(void* const* d_in, const int* in_sizes, int n_in,
                              void* d_out, int out_size, void* d_ws, size_t ws_size,
                              hipStream_t stream) {
    const float* t     = (const float*)d_in[0];
    const float* y     = (const float*)d_in[1];
    const float* w1    = (const float*)d_in[2];
    const float* b1    = (const float*)d_in[3];
    const float* w2    = (const float*)d_in[4];
    const float* b2    = (const float*)d_in[5];
    const float* w3    = (const float*)d_in[6];
    const float* b3    = (const float*)d_in[7];
    const float* w4    = (const float*)d_in[8];
    const float* b4    = (const float*)d_in[9];
    const float* beta  = (const float*)d_in[10];
    const float* gamma = (const float*)d_in[11];

    float* me  = (float*)d_ws;    // 1024 floats of scratch
    float* out = (float*)d_out;

    me_kernel<<<T_N / 256, 256, 0, stream>>>(t, w1, b1, w2, b2, w3, b3, w4, b4, me);
    scan_kernel<<<B_N, 256, 0, stream>>>(t, y, beta, gamma, me, out);
}

// Round 3
// 154.787 us; speedup vs baseline: 1.9913x; 1.0481x over previous
//
#include <hip/hip_runtime.h>

// Problem constants: T=1024, B=256, H=20
#define T_N 1024
#define B_N 256
#define H_N 20
#define SRW (T_N + 65)   // shifted-me row stride: 1089 ≡ 1 (mod 32)
#define NW  8            // waves per block
#define NDW (NW - 1)     // dot waves

__device__ __forceinline__ float rdlane(float v, int lane) {
    return __uint_as_float((unsigned)__builtin_amdgcn_readlane((int)__float_as_uint(v), lane));
}
__device__ __forceinline__ float comp(const float4& v, const int i) {
    return i == 0 ? v.x : i == 1 ? v.y : i == 2 ? v.z : v.w;
}
__device__ __forceinline__ float fast_tanh(float x) {
    const float e = __expf(2.0f * x);
    return fmaf(-2.0f, __builtin_amdgcn_rcpf(e + 1.0f), 1.0f);
}
__device__ __forceinline__ float fast_sigmoid(float x) {
    return __builtin_amdgcn_rcpf(1.0f + __expf(-x));
}

// ---------------------------------------------------------------------------
// Single fused kernel. 256 blocks (1/batch) x 512 threads (8 waves).
// Phase A: all waves redundantly compute me[1024] (2 t-values/thread) into
//          the 4-shifted LDS image sR (fast tanh/sigmoid, uniform weight
//          loads scalarize to s_load; no weight staging needed).
// Phase B: wave 0 runs the serial SIR chain (LDS-free inner loop, register
//          me-tables, deferred readlane); waves 1-7 compute history dots for
//          the next chunk (float4, 2x unrolled, 7-way strided).
// ---------------------------------------------------------------------------
__global__ __launch_bounds__(512, 1) void scan_kernel(
    const float* __restrict__ t,
    const float* __restrict__ y,
    const float* __restrict__ w1, const float* __restrict__ b1,
    const float* __restrict__ w2, const float* __restrict__ b2,
    const float* __restrict__ w3, const float* __restrict__ b3,
    const float* __restrict__ w4, const float* __restrict__ b4,
    const float* __restrict__ beta_p,
    const float* __restrict__ gamma_p,
    float* __restrict__ out)     // [solution (T*B*3) | diff (T*B*3)]
{
    __shared__ __align__(16) float sR[4 * SRW];
    __shared__ __align__(16) float sI[T_N];
    __shared__ float P[2][NDW][64];

    const int b   = blockIdx.x;
    const int tid = threadIdx.x;
    const int wid = tid >> 6;
    const int L   = tid & 63;

    // ---- Phase A: me MLP (2 values per thread) + zero padding of sR ----
    for (int idx = tid; idx < 4 * SRW; idx += 512) {
        const int r = idx / SRW;
        const int x = idx - r * SRW;
        if (x + r >= T_N) sR[idx] = 0.0f;
    }

#pragma unroll
    for (int v = 0; v < 2; ++v) {
        const int mi = tid + v * 512;
        const float x = t[mi];

        float h1[H_N], h2[H_N];
#pragma unroll
        for (int k = 0; k < H_N; ++k) h1[k] = fast_tanh(fmaf(x, w1[k], b1[k]));

#pragma unroll 4
        for (int k = 0; k < H_N; ++k) {
            float a = b2[k];
#pragma unroll
            for (int j = 0; j < H_N; ++j) a = fmaf(h1[j], w2[j * H_N + k], a);
            h2[k] = fast_tanh(a);
        }

        float a4 = b4[0];
#pragma unroll 4
        for (int k = 0; k < H_N; ++k) {
            float a = b3[k];
#pragma unroll
            for (int j = 0; j < H_N; ++j) a = fmaf(h2[j], w3[j * H_N + k], a);
            a4 = fmaf(fast_tanh(a), w4[k], a4);
        }

        const float meval = fast_sigmoid(a4);
#pragma unroll
        for (int r = 0; r < 4; ++r) {
            const int xx = mi - r;
            if (xx >= 0) sR[r * SRW + xx] = meval;
        }
    }

    // ---- scalars / state ----
    const float dt   = t[0] - t[1];
    const float beta = beta_p[0];
    const float gma  = gamma_p[0];
    const float dtb  = dt * beta;       // dt*beta
    const float ndtg = -dt * gma;       // -dt*gamma
    const float dt2  = dt * dt;
    const float invdt = 1.0f / dt;

    const float S0 = y[b * 3 + 0];
    const float I0 = y[b * 3 + 1];
    const float R0 = y[b * 3 + 2];
    const float TOT = S0 + I0 + R0;     // SIR total is conserved (d0+d1+d2=0)

    float S = S0, I = I0;

    if (tid == 0) sI[0] = I0;

    float* __restrict__ diff = out + (size_t)T_N * B_N * 3;
    if (tid < 3) diff[((size_t)(T_N - 1) * B_N + b) * 3 + tid] = 0.0f;

    __syncthreads();   // sR, sI[0] visible

    const float meT1 = sR[T_N - 1];     // me[T-1], wave-uniform

    // wave-0 register me-tables
    float4 rm4[16], rn4[16];
    if (wid == 0) {
        const int b0 = T_N - L;         // rm[m] = me_pad[T-L+m] (0 for m>=L)
        const int r0 = b0 & 3;
        const float* p0 = &sR[r0 * SRW + (b0 - r0)];
        const int b2i = T_N - 64 - L;   // rn[m] = me[T-64-L+m]
        const int r2 = b2i & 3;
        const float* p2 = &sR[r2 * SRW + (b2i - r2)];
#pragma unroll
        for (int k = 0; k < 16; ++k) {
            rm4[k] = *(const float4*)&p0[4 * k];
            rn4[k] = *(const float4*)&p2[4 * k];
        }
    }

    float acc_cur = 0.0f, acc_nxt = 0.0f, pre = 0.0f;
    float oS = S0, oI = I0;
    float carryS = S0, carryI = I0;

    // STEP(m): entering (S,I) = y_{64c+m-1}; produces y_{64c+m}.
    // pre for step m was read BEFORE step (m-1)'s fold -> patch with meT1*I.
#define STEP(m_, first_)                                                  \
    {                                                                     \
        const float sum = (first_) ? pre : fmaf(meT1, I, pre);            \
        float pnx = pre;                                                  \
        if ((m_) < 63) pnx = rdlane(acc_cur, (m_) + 1);                   \
        const float a  = dtb * S;                                         \
        const float q  = a * I;                                           \
        const float i1 = fmaf(ndtg, I, I);                                \
        const float s1 = S - q;                                           \
        S = fmaf(dt2, sum, s1);                                           \
        I = i1 + q;                                                       \
        const bool cap = (L == (m_));                                     \
        oS = cap ? S : oS;                                                \
        oI = cap ? I : oI;                                                \
        acc_cur = fmaf(comp(rm4[(m_) >> 2], (m_) & 3), I, acc_cur);       \
        acc_nxt = fmaf(comp(rn4[(m_) >> 2], (m_) & 3), I, acc_nxt);       \
        pre = pnx;                                                        \
    }

    for (int c = 0; c < 16; ++c) {
        if (wid == 0) {
            if (c == 0) {
                // fold initial I0 (t=0 term); lane0's rm[0] is the 0 pad
                acc_cur = comp(rm4[0], 0) * I;
                acc_nxt = comp(rn4[0], 0) * I;
                pre = rdlane(acc_cur, 1);
#pragma unroll
                for (int m = 1; m < 64; ++m) STEP(m, m == 1)
            } else {
                acc_cur = acc_nxt;
#pragma unroll
                for (int w = 0; w < NDW; ++w) acc_cur += P[c & 1][w][L];
                acc_nxt = 0.0f;
                pre = rdlane(acc_cur, 0);
#pragma unroll
                for (int m = 0; m < 64; ++m) STEP(m, m == 0)
            }

            // ---- chunk epilogue (wave 0) ----
            const int j = 64 * c + L;
            sI[j] = oI;
            const float oR = TOT - oS - oI;
            const size_t so = ((size_t)j * B_N + b) * 3;
            out[so + 0] = oS;
            out[so + 1] = oI;
            out[so + 2] = oR;

            // diff rows j-1 = 64c+L-1 (chunk0 lane0 skipped)
            float sm1 = __shfl_up(oS, 1);
            float im1 = __shfl_up(oI, 1);
            if (L == 0) { sm1 = carryS; im1 = carryI; }
            if (j > 0) {
                const float d0 = (oS - sm1) * invdt;
                const float d1 = (oI - im1) * invdt;
                const float d2 = -d0 - d1;
                const size_t dofs = ((size_t)(j - 1) * B_N + b) * 3;
                diff[dofs + 0] = d0;
                diff[dofs + 1] = d1;
                diff[dofs + 2] = d2;
            }
            carryS = rdlane(oS, 63);
            carryI = rdlane(oI, 63);
        } else if (c < 15) {
            // history dot for chunk c+1 over t < 64c, 7-way strided, 2x unroll
            const int w  = wid - 1;
            const int bc = T_N - 64 * (c + 1) - L;
            const int rc = bc & 3;
            const float* mp = &sR[rc * SRW + (bc - rc)];
            const float4* iv4 = (const float4*)sI;
            float p0 = 0.0f, p1 = 0.0f;
            int q = w;
            const int end = 16 * c;
            for (; q + NDW < end; q += 2 * NDW) {
                const float4 A0 = *(const float4*)&mp[4 * q];
                const float4 A1 = *(const float4*)&mp[4 * (q + NDW)];
                const float4 B0 = iv4[q];
                const float4 B1 = iv4[q + NDW];
                p0 += (A0.x * B0.x + A0.y * B0.y) + (A0.z * B0.z + A0.w * B0.w);
                p1 += (A1.x * B1.x + A1.y * B1.y) + (A1.z * B1.z + A1.w * B1.w);
            }
            if (q < end) {
                const float4 A0 = *(const float4*)&mp[4 * q];
                const float4 B0 = iv4[q];
                p0 += (A0.x * B0.x + A0.y * B0.y) + (A0.z * B0.z + A0.w * B0.w);
            }
            P[(c + 1) & 1][w][L] = p0 + p1;
        }
        __syncthreads();
    }
#undef STEP
}

// ---------------------------------------------------------------------------
// Launcher
// ---------------------------------------------------------------------------
extern "C" void kernel_launch(void* const* d_in, const int* in_sizes, int n_in,
                              void* d_out, int out_size, void* d_ws, size_t ws_size,
                              hipStream_t stream) {
    const float* t     = (const float*)d_in[0];
    const float* y     = (const float*)d_in[1];
    const float* w1    = (const float*)d_in[2];
    const float* b1    = (const float*)d_in[3];
    const float* w2    = (const float*)d_in[4];
    const float* b2    = (const float*)d_in[5];
    const float* w3    = (const float*)d_in[6];
    const float* b3    = (const float*)d_in[7];
    const float* w4    = (const float*)d_in[8];
    const float* b4    = (const float*)d_in[9];
    const float* beta  = (const float*)d_in[10];
    const float* gamma = (const float*)d_in[11];

    scan_kernel<<<B_N, 512, 0, stream>>>(t, y, w1, b1, w2, b2, w3, b3, w4, b4,
                                         beta, gamma, (float*)d_out);
}

// Round 4
// 132.766 us; speedup vs baseline: 2.3215x; 1.1659x over previous
//
#include <hip/hip_runtime.h>

// Problem constants: T=1024, B=256, H=20
#define T_N 1024
#define B_N 256
#define H_N 20
#define SRW 1092         // shifted-me row stride: multiple of 4 (aligned float4), ≡4 mod 32
#define NW  8            // waves per block
#define NDW (NW - 1)     // dot waves

__device__ __forceinline__ float rdlane_i(float v, int lane) {
    return __uint_as_float((unsigned)__builtin_amdgcn_readlane((int)__float_as_uint(v), lane));
}
template <int I4>
__device__ __forceinline__ float comp4(const float4& v) {
    if constexpr (I4 == 0) return v.x;
    else if constexpr (I4 == 1) return v.y;
    else if constexpr (I4 == 2) return v.z;
    else return v.w;
}
__device__ __forceinline__ float fast_tanh(float x) {
    const float e = __expf(2.0f * x);
    return fmaf(-2.0f, __builtin_amdgcn_rcpf(e + 1.0f), 1.0f);
}
__device__ __forceinline__ float fast_sigmoid(float x) {
    return __builtin_amdgcn_rcpf(1.0f + __expf(-x));
}

// compile-time loop: guarantees static indices (register tables stay in VGPRs)
template <int M, int END, class F>
__device__ __forceinline__ void unroll_range(F&& f) {
    if constexpr (M < END) {
        f.template step<M>();
        unroll_range<M + 1, END>(static_cast<F&&>(f));
    }
}

// ---------------------------------------------------------------------------
// Single fused kernel. 256 blocks (1/batch) x 512 threads (8 waves).
// Phase A: all waves redundantly compute me[1024] into the 4-shifted LDS
//          image sR. Phase B: wave 0 runs the serial SIR chain with
//          register me-tables (template-forced full unroll, static readlane);
//          waves 1-7 compute history dots for the next chunk.
// ---------------------------------------------------------------------------
struct SerialCtx {
    float4 rm4[16], rn4[16];
    float S, I, oS, oI;
    float acc_cur, acc_nxt, pre;
    float meT1, dtb, ndtg, dt2;
    int L;

    template <int M>
    __device__ __forceinline__ void dostep(const bool first) {
        const float sum = first ? pre : fmaf(meT1, I, pre);
        float pnx = pre;
        if constexpr (M < 63) pnx = rdlane_i(acc_cur, M + 1);   // immediate lane
        const float a  = dtb * S;
        const float q  = a * I;
        const float i1 = fmaf(ndtg, I, I);
        const float s1 = S - q;
        S = fmaf(dt2, sum, s1);
        I = i1 + q;
        const bool cap = (L == M);
        oS = cap ? S : oS;
        oI = cap ? I : oI;
        acc_cur = fmaf(comp4<(M & 3)>(rm4[M >> 2]), I, acc_cur);
        acc_nxt = fmaf(comp4<(M & 3)>(rn4[M >> 2]), I, acc_nxt);
        pre = pnx;
    }
    template <int M>
    __device__ __forceinline__ void step() { dostep<M>(false); }
};

__global__ __launch_bounds__(512, 1) void scan_kernel(
    const float* __restrict__ t,
    const float* __restrict__ y,
    const float* __restrict__ w1, const float* __restrict__ b1,
    const float* __restrict__ w2, const float* __restrict__ b2,
    const float* __restrict__ w3, const float* __restrict__ b3,
    const float* __restrict__ w4, const float* __restrict__ b4,
    const float* __restrict__ beta_p,
    const float* __restrict__ gamma_p,
    float* __restrict__ out)     // [solution (T*B*3) | diff (T*B*3)]
{
    __shared__ __align__(16) float sR[4 * SRW];
    __shared__ __align__(16) float sI[T_N];
    __shared__ float P[2][NDW][64];

    const int b   = blockIdx.x;
    const int tid = threadIdx.x;
    const int wid = tid >> 6;
    const int L   = tid & 63;

    // ---- Phase A: me MLP (2 values/thread) + zero padding of sR ----
    for (int idx = tid; idx < 4 * SRW; idx += 512) {
        const int r = idx / SRW;
        const int x = idx - r * SRW;
        if (x + r >= T_N) sR[idx] = 0.0f;
    }

#pragma unroll
    for (int v = 0; v < 2; ++v) {
        const int mi = tid + v * 512;
        const float x = t[mi];

        float h1[H_N], h2[H_N];
#pragma unroll
        for (int k = 0; k < H_N; ++k) h1[k] = fast_tanh(fmaf(x, w1[k], b1[k]));

#pragma unroll 4
        for (int k = 0; k < H_N; ++k) {
            float a = b2[k];
#pragma unroll
            for (int j = 0; j < H_N; ++j) a = fmaf(h1[j], w2[j * H_N + k], a);
            h2[k] = fast_tanh(a);
        }

        float a4 = b4[0];
#pragma unroll 4
        for (int k = 0; k < H_N; ++k) {
            float a = b3[k];
#pragma unroll
            for (int j = 0; j < H_N; ++j) a = fmaf(h2[j], w3[j * H_N + k], a);
            a4 = fmaf(fast_tanh(a), w4[k], a4);
        }

        const float meval = fast_sigmoid(a4);
#pragma unroll
        for (int r = 0; r < 4; ++r) {
            const int xx = mi - r;
            if (xx >= 0) sR[r * SRW + xx] = meval;
        }
    }

    // ---- scalars / state ----
    const float dt    = t[0] - t[1];
    const float beta  = beta_p[0];
    const float gma   = gamma_p[0];
    const float invdt = 1.0f / dt;

    const float S0 = y[b * 3 + 0];
    const float I0 = y[b * 3 + 1];
    const float R0 = y[b * 3 + 2];
    const float TOT = S0 + I0 + R0;     // SIR total conserved (d0+d1+d2=0)

    if (tid == 0) sI[0] = I0;

    float* __restrict__ diff = out + (size_t)T_N * B_N * 3;
    if (tid < 3) diff[((size_t)(T_N - 1) * B_N + b) * 3 + tid] = 0.0f;

    __syncthreads();   // sR, sI[0] visible

    SerialCtx cx;
    cx.S = S0; cx.I = I0; cx.oS = S0; cx.oI = I0;
    cx.acc_cur = 0.0f; cx.acc_nxt = 0.0f; cx.pre = 0.0f;
    cx.meT1 = sR[T_N - 1];
    cx.dtb  = dt * beta;
    cx.ndtg = -dt * gma;
    cx.dt2  = dt * dt;
    cx.L    = L;

    float carryS = S0, carryI = I0;

    if (wid == 0) {
        // rm[m] = me_pad[T-L+m] (0 for m>=L); rn[m] = me[T-64-L+m]
        const int b0 = T_N - L;
        const int r0 = b0 & 3;
        const float* p0 = &sR[r0 * SRW + (b0 - r0)];
        const int b2i = T_N - 64 - L;
        const int r2 = b2i & 3;
        const float* p2 = &sR[r2 * SRW + (b2i - r2)];
#pragma unroll
        for (int k = 0; k < 16; ++k) {
            cx.rm4[k] = *(const float4*)&p0[4 * k];
            cx.rn4[k] = *(const float4*)&p2[4 * k];
        }
    }

    for (int c = 0; c < 16; ++c) {
        if (wid == 0) {
            if (c == 0) {
                // fold initial I0 (t=0 term); lane0's rm[0].x is the 0 pad
                cx.acc_cur = comp4<0>(cx.rm4[0]) * cx.I;
                cx.acc_nxt = comp4<0>(cx.rn4[0]) * cx.I;
                cx.pre = rdlane_i(cx.acc_cur, 1);
                cx.dostep<1>(true);
                unroll_range<2, 64>(cx);
            } else {
                float ac = cx.acc_nxt;
#pragma unroll
                for (int w = 0; w < NDW; ++w) ac += P[c & 1][w][L];
                cx.acc_cur = ac;
                cx.acc_nxt = 0.0f;
                cx.pre = rdlane_i(cx.acc_cur, 0);
                cx.dostep<0>(true);
                unroll_range<1, 64>(cx);
            }

            // ---- chunk epilogue (wave 0) ----
            const int j = 64 * c + L;
            sI[j] = cx.oI;
            const float oR = TOT - cx.oS - cx.oI;
            const size_t so = ((size_t)j * B_N + b) * 3;
            out[so + 0] = cx.oS;
            out[so + 1] = cx.oI;
            out[so + 2] = oR;

            float sm1 = __shfl_up(cx.oS, 1);
            float im1 = __shfl_up(cx.oI, 1);
            if (L == 0) { sm1 = carryS; im1 = carryI; }
            if (j > 0) {
                const float d0 = (cx.oS - sm1) * invdt;
                const float d1 = (cx.oI - im1) * invdt;
                const float d2 = -d0 - d1;
                const size_t dofs = ((size_t)(j - 1) * B_N + b) * 3;
                diff[dofs + 0] = d0;
                diff[dofs + 1] = d1;
                diff[dofs + 2] = d2;
            }
            carryS = rdlane_i(cx.oS, 63);
            carryI = rdlane_i(cx.oI, 63);
        } else if (c < 15) {
            // history dot for chunk c+1 over t < 64c, 7-way strided, 2x unroll
            const int w  = wid - 1;
            const int bc = T_N - 64 * (c + 1) - L;
            const int rc = bc & 3;
            const float* mp = &sR[rc * SRW + (bc - rc)];   // 16B-aligned now
            const float4* iv4 = (const float4*)sI;
            float p0 = 0.0f, p1 = 0.0f;
            int q = w;
            const int end = 16 * c;
            for (; q + NDW < end; q += 2 * NDW) {
                const float4 A0 = *(const float4*)&mp[4 * q];
                const float4 A1 = *(const float4*)&mp[4 * (q + NDW)];
                const float4 B0 = iv4[q];
                const float4 B1 = iv4[q + NDW];
                p0 += (A0.x * B0.x + A0.y * B0.y) + (A0.z * B0.z + A0.w * B0.w);
                p1 += (A1.x * B1.x + A1.y * B1.y) + (A1.z * B1.z + A1.w * B1.w);
            }
            if (q < end) {
                const float4 A0 = *(const float4*)&mp[4 * q];
                const float4 B0 = iv4[q];
                p0 += (A0.x * B0.x + A0.y * B0.y) + (A0.z * B0.z + A0.w * B0.w);
            }
            P[(c + 1) & 1][w][L] = p0 + p1;
        }
        __syncthreads();
    }
}

// ---------------------------------------------------------------------------
// Launcher
// ---------------------------------------------------------------------------
extern "C" void kernel_launch(void* const* d_in, const int* in_sizes, int n_in,
                              void* d_out, int out_size, void* d_ws, size_t ws_size,
                              hipStream_t stream) {
    const float* t     = (const float*)d_in[0];
    const float* y     = (const float*)d_in[1];
    const float* w1    = (const float*)d_in[2];
    const float* b1    = (const float*)d_in[3];
    const float* w2    = (const float*)d_in[4];
    const float* b2    = (const float*)d_in[5];
    const float* w3    = (const float*)d_in[6];
    const float* b3    = (const float*)d_in[7];
    const float* w4    = (const float*)d_in[8];
    const float* b4    = (const float*)d_in[9];
    const float* beta  = (const float*)d_in[10];
    const float* gamma = (const float*)d_in[11];

    scan_kernel<<<B_N, 512, 0, stream>>>(t, y, w1, b1, w2, b2, w3, b3, w4, b4,
                                         beta, gamma, (float*)d_out);
}

// Round 5
// 128.050 us; speedup vs baseline: 2.4071x; 1.0368x over previous
//
#include <hip/hip_runtime.h>

// Problem constants: T=1024, B=256, H=20
#define T_N 1024
#define B_N 256
#define H_N 20
#define NW  8            // waves per block
#define NDW (NW - 1)     // dot waves
#define SIH 1096         // I-history row stride in HALVES: ≡8 mod 64 → the 8 rows
                         // sit 4 words apart mod 32 → 8 b128 broadcasts on
                         // disjoint banks = conflict-free

typedef _Float16 h8_t __attribute__((ext_vector_type(8)));
typedef _Float16 h2_t __attribute__((ext_vector_type(2)));

#if __has_builtin(__builtin_amdgcn_fdot2)
#define DOT8(acc, mv, iv)                                                           \
    acc = __builtin_amdgcn_fdot2(__builtin_shufflevector(mv, mv, 0, 1),             \
                                 __builtin_shufflevector(iv, iv, 0, 1), acc, false);\
    acc = __builtin_amdgcn_fdot2(__builtin_shufflevector(mv, mv, 2, 3),             \
                                 __builtin_shufflevector(iv, iv, 2, 3), acc, false);\
    acc = __builtin_amdgcn_fdot2(__builtin_shufflevector(mv, mv, 4, 5),             \
                                 __builtin_shufflevector(iv, iv, 4, 5), acc, false);\
    acc = __builtin_amdgcn_fdot2(__builtin_shufflevector(mv, mv, 6, 7),             \
                                 __builtin_shufflevector(iv, iv, 6, 7), acc, false);
#else
#define DOT8(acc, mv, iv)                                                           \
    _Pragma("unroll")                                                               \
    for (int _k = 0; _k < 8; ++_k) acc = fmaf((float)mv[_k], (float)iv[_k], acc);
#endif

__device__ __forceinline__ float rdlane_i(float v, int lane) {
    return __uint_as_float((unsigned)__builtin_amdgcn_readlane((int)__float_as_uint(v), lane));
}
template <int I4>
__device__ __forceinline__ float comp4(const float4& v) {
    if constexpr (I4 == 0) return v.x;
    else if constexpr (I4 == 1) return v.y;
    else if constexpr (I4 == 2) return v.z;
    else return v.w;
}
__device__ __forceinline__ float fast_tanh(float x) {
    const float e = __expf(2.0f * x);
    return fmaf(-2.0f, __builtin_amdgcn_rcpf(e + 1.0f), 1.0f);
}
__device__ __forceinline__ float fast_sigmoid(float x) {
    return __builtin_amdgcn_rcpf(1.0f + __expf(-x));
}

template <int M, int END, class F>
__device__ __forceinline__ void unroll_range(F&& f) {
    if constexpr (M < END) {
        f.template step<M>();
        unroll_range<M + 1, END>(static_cast<F&&>(f));
    }
}

// ---------------------------------------------------------------------------
// Serial context (wave 0): template-unrolled 64-step SIR chain.
// ---------------------------------------------------------------------------
struct SerialCtx {
    float4 rm4[16], rn4[16];
    float S, I, oS, oI;
    float acc_cur, acc_nxt, pre;
    float meT1, dtb, ndtg, dt2;
    int L;

    template <int M>
    __device__ __forceinline__ void dostep(const bool first) {
        const float sum = first ? pre : fmaf(meT1, I, pre);
        float pnx = pre;
        if constexpr (M < 63) pnx = rdlane_i(acc_cur, M + 1);
        const float a  = dtb * S;
        const float q  = a * I;
        const float i1 = fmaf(ndtg, I, I);
        const float s1 = S - q;
        S = fmaf(dt2, sum, s1);
        I = i1 + q;
        const bool cap = (L == M);
        oS = cap ? S : oS;
        oI = cap ? I : oI;
        acc_cur = fmaf(comp4<(M & 3)>(rm4[M >> 2]), I, acc_cur);
        acc_nxt = fmaf(comp4<(M & 3)>(rn4[M >> 2]), I, acc_nxt);
        pre = pnx;
    }
    template <int M>
    __device__ __forceinline__ void step() { dostep<M>(false); }
};

// ---------------------------------------------------------------------------
// Single fused kernel. 256 blocks (1/batch) x 512 threads (8 waves).
// Phase A: all waves compute me[1024] -> fp32 sMeF + fp16 sMeH.
// Phase B: wave 0 = serial SIR chain; waves 1-7 = fp16 fdot2 history dots
//          (me: single-copy aligned-down b128, ~2 addrs/bank; I: 8 shifted
//          fp16 rows, per-class broadcast on disjoint banks).
// ---------------------------------------------------------------------------
__global__ __launch_bounds__(512, 1) void scan_kernel(
    const float* __restrict__ t,
    const float* __restrict__ y,
    const float* __restrict__ w1, const float* __restrict__ b1,
    const float* __restrict__ w2, const float* __restrict__ b2,
    const float* __restrict__ w3, const float* __restrict__ b3,
    const float* __restrict__ w4, const float* __restrict__ b4,
    const float* __restrict__ beta_p,
    const float* __restrict__ gamma_p,
    float* __restrict__ out)     // [solution (T*B*3) | diff (T*B*3)]
{
    __shared__ __align__(16) float    sMeF[T_N];      // fp32 me (serial tables + fixup)
    __shared__ __align__(16) _Float16 sMeH[T_N];      // fp16 me (dot operand A)
    __shared__ __align__(16) _Float16 sIhR[8 * SIH];  // 8 shifted fp16 I-history rows
    __shared__ float P[2][NDW][64];

    const int b   = blockIdx.x;
    const int tid = threadIdx.x;
    const int wid = tid >> 6;
    const int L   = tid & 63;

    // per-lane dot-geometry constants (chunk-invariant)
    const int f    = (-L) & 7;            // misalignment of lane L's me window
    const int R8   = L + f;               // L rounded up to multiple of 8
    const int row  = L & 7;               // I-history row for this lane
    const int iofs = row * SIH + (f ? 0 : 8);

    // zero the row front-pads (slots representing I[<0])
    if (tid < 64) sIhR[(tid >> 3) * SIH + (tid & 7)] = (_Float16)0.0f;

    // ---- Phase A: me MLP (2 values/thread) ----
#pragma unroll
    for (int v = 0; v < 2; ++v) {
        const int mi = tid + v * 512;
        const float x = t[mi];

        float h1[H_N], h2[H_N];
#pragma unroll
        for (int k = 0; k < H_N; ++k) h1[k] = fast_tanh(fmaf(x, w1[k], b1[k]));

#pragma unroll 4
        for (int k = 0; k < H_N; ++k) {
            float a = b2[k];
#pragma unroll
            for (int j = 0; j < H_N; ++j) a = fmaf(h1[j], w2[j * H_N + k], a);
            h2[k] = fast_tanh(a);
        }

        float a4 = b4[0];
#pragma unroll 4
        for (int k = 0; k < H_N; ++k) {
            float a = b3[k];
#pragma unroll
            for (int j = 0; j < H_N; ++j) a = fmaf(h2[j], w3[j * H_N + k], a);
            a4 = fmaf(fast_tanh(a), w4[k], a4);
        }

        const float meval = fast_sigmoid(a4);
        sMeF[mi] = meval;
        sMeH[mi] = (_Float16)meval;
    }

    // ---- scalars / state ----
    const float dt    = t[0] - t[1];
    const float beta  = beta_p[0];
    const float gma   = gamma_p[0];
    const float invdt = 1.0f / dt;

    const float S0 = y[b * 3 + 0];
    const float I0 = y[b * 3 + 1];
    const float R0 = y[b * 3 + 2];
    const float TOT = S0 + I0 + R0;     // SIR total conserved

    // publish I[0] into all 8 rows
    if (tid < 8) sIhR[tid * SIH + 8 - tid] = (_Float16)I0;

    float* __restrict__ diff = out + (size_t)T_N * B_N * 3;
    if (tid < 3) diff[((size_t)(T_N - 1) * B_N + b) * 3 + tid] = 0.0f;

    __syncthreads();   // sMeF/sMeH/pads/I0 visible

    // fixup me weights (chunk-invariant): mf[d-1] = me[960 - L - d]
    float mf[7];
#pragma unroll
    for (int d = 1; d <= 7; ++d) mf[d - 1] = sMeF[T_N - 64 - L - d];

    SerialCtx cx;
    cx.S = S0; cx.I = I0; cx.oS = S0; cx.oI = I0;
    cx.acc_cur = 0.0f; cx.acc_nxt = 0.0f; cx.pre = 0.0f;
    cx.meT1 = sMeF[T_N - 1];
    cx.dtb  = dt * beta;
    cx.ndtg = -dt * gma;
    cx.dt2  = dt * dt;
    cx.L    = L;

    float carryS = S0, carryI = I0;

    if (wid == 0) {
        // rm[m] = me_pad[T-L+m] (0 for m>=L); rn[m] = me[T-64-L+m]
        float* rmf = (float*)cx.rm4;
        float* rnf = (float*)cx.rn4;
#pragma unroll
        for (int m = 0; m < 64; ++m) {
            rmf[m] = (m < L) ? sMeF[T_N - L + m] : 0.0f;
            rnf[m] = sMeF[T_N - 64 - L + m];
        }
    }

    for (int c = 0; c < 16; ++c) {
        if (wid == 0) {
            if (c == 0) {
                cx.acc_cur = comp4<0>(cx.rm4[0]) * cx.I;
                cx.acc_nxt = comp4<0>(cx.rn4[0]) * cx.I;
                cx.pre = rdlane_i(cx.acc_cur, 1);
                cx.dostep<1>(true);
                unroll_range<2, 64>(cx);
            } else {
                float ac = cx.acc_nxt;
#pragma unroll
                for (int w = 0; w < NDW; ++w) ac += P[c & 1][w][L];
                cx.acc_cur = ac;
                cx.acc_nxt = 0.0f;
                cx.pre = rdlane_i(cx.acc_cur, 0);
                cx.dostep<0>(true);
                unroll_range<1, 64>(cx);
            }

            // ---- chunk epilogue (wave 0) ----
            const int j = 64 * c + L;
            const _Float16 hI = (_Float16)cx.oI;
#pragma unroll
            for (int r = 0; r < 8; ++r) sIhR[r * SIH + 8 + (j - r)] = hI;

            const float oR = TOT - cx.oS - cx.oI;
            const size_t so = ((size_t)j * B_N + b) * 3;
            out[so + 0] = cx.oS;
            out[so + 1] = cx.oI;
            out[so + 2] = oR;

            float sm1 = __shfl_up(cx.oS, 1);
            float im1 = __shfl_up(cx.oI, 1);
            if (L == 0) { sm1 = carryS; im1 = carryI; }
            if (j > 0) {
                const float d0 = (cx.oS - sm1) * invdt;
                const float d1 = (cx.oI - im1) * invdt;
                const float d2 = -d0 - d1;
                const size_t dofs = ((size_t)(j - 1) * B_N + b) * 3;
                diff[dofs + 0] = d0;
                diff[dofs + 1] = d1;
                diff[dofs + 2] = d2;
            }
            carryS = rdlane_i(cx.oS, 63);
            carryI = rdlane_i(cx.oI, 63);
        } else if (c < 15) {
            // history dot for chunk c+1 over tau < 64c:
            //   acc_L = sum_s  me_h[idx0 + 8s + k] * I_h[row][iofs + 8s + k]
            // (front k<f terms hit zero pads; missing tail terms tau in
            //  [64c-f, 64c) are fixed up by wave w==0 with register weights)
            const int w    = wid - 1;
            const int G    = 8 * c;
            const int idx0 = (T_N - 64 * (c + 1)) - R8;
            float p0 = 0.0f, p1 = 0.0f;
            int s = w;
            for (; s + NDW < G; s += 2 * NDW) {
                const h8_t mv0 = *(const h8_t*)&sMeH[idx0 + 8 * s];
                const h8_t iv0 = *(const h8_t*)&sIhR[iofs + 8 * s];
                const h8_t mv1 = *(const h8_t*)&sMeH[idx0 + 8 * (s + NDW)];
                const h8_t iv1 = *(const h8_t*)&sIhR[iofs + 8 * (s + NDW)];
                DOT8(p0, mv0, iv0)
                DOT8(p1, mv1, iv1)
            }
            if (s < G) {
                const h8_t mv0 = *(const h8_t*)&sMeH[idx0 + 8 * s];
                const h8_t iv0 = *(const h8_t*)&sIhR[iofs + 8 * s];
                DOT8(p0, mv0, iv0)
            }
            float p = p0 + p1;
            if (w == 0) {
                // tail fixup: tau = 64c - d, d = 1..f  (c==0 reads zero pads)
#pragma unroll
                for (int d = 1; d <= 7; ++d) {
                    const float ih = (float)sIhR[8 + 64 * c - d];   // row 0
                    if (d <= f) p = fmaf(mf[d - 1], ih, p);
                }
            }
            P[(c + 1) & 1][w][L] = p;
        }
        __syncthreads();
    }
}

// ---------------------------------------------------------------------------
// Launcher
// ---------------------------------------------------------------------------
extern "C" void kernel_launch(void* const* d_in, const int* in_sizes, int n_in,
                              void* d_out, int out_size, void* d_ws, size_t ws_size,
                              hipStream_t stream) {
    const float* t     = (const float*)d_in[0];
    const float* y     = (const float*)d_in[1];
    const float* w1    = (const float*)d_in[2];
    const float* b1    = (const float*)d_in[3];
    const float* w2    = (const float*)d_in[4];
    const float* b2    = (const float*)d_in[5];
    const float* w3    = (const float*)d_in[6];
    const float* b3    = (const float*)d_in[7];
    const float* w4    = (const float*)d_in[8];
    const float* b4    = (const float*)d_in[9];
    const float* beta  = (const float*)d_in[10];
    const float* gamma = (const float*)d_in[11];

    scan_kernel<<<B_N, 512, 0, stream>>>(t, y, w1, b1, w2, b2, w3, b3, w4, b4,
                                         beta, gamma, (float*)d_out);
}

// Round 6
// 121.931 us; speedup vs baseline: 2.5278x; 1.0502x over previous
//
#include <hip/hip_runtime.h>

// Problem constants: T=1024, B=256, H=20
#define T_N 1024
#define B_N 256
#define H_N 20
#define NW  8            // waves per block
#define NDW (NW - 1)     // dot waves
#define SIH 1096         // I-history row stride in HALVES (conflict-free layout, see R5)

typedef _Float16 h8_t __attribute__((ext_vector_type(8)));

#if __has_builtin(__builtin_amdgcn_fdot2)
#define DOT8(acc, mv, iv)                                                           \
    acc = __builtin_amdgcn_fdot2(__builtin_shufflevector(mv, mv, 0, 1),             \
                                 __builtin_shufflevector(iv, iv, 0, 1), acc, false);\
    acc = __builtin_amdgcn_fdot2(__builtin_shufflevector(mv, mv, 2, 3),             \
                                 __builtin_shufflevector(iv, iv, 2, 3), acc, false);\
    acc = __builtin_amdgcn_fdot2(__builtin_shufflevector(mv, mv, 4, 5),             \
                                 __builtin_shufflevector(iv, iv, 4, 5), acc, false);\
    acc = __builtin_amdgcn_fdot2(__builtin_shufflevector(mv, mv, 6, 7),             \
                                 __builtin_shufflevector(iv, iv, 6, 7), acc, false);
#else
#define DOT8(acc, mv, iv)                                                           \
    _Pragma("unroll")                                                               \
    for (int _k = 0; _k < 8; ++_k) acc = fmaf((float)mv[_k], (float)iv[_k], acc);
#endif

__device__ __forceinline__ float rdlane_i(float v, int lane) {
    return __uint_as_float((unsigned)__builtin_amdgcn_readlane((int)__float_as_uint(v), lane));
}
__device__ __forceinline__ float fast_tanh(float x) {
    const float e = __expf(2.0f * x);
    return fmaf(-2.0f, __builtin_amdgcn_rcpf(e + 1.0f), 1.0f);
}
__device__ __forceinline__ float fast_sigmoid(float x) {
    return __builtin_amdgcn_rcpf(1.0f + __expf(-x));
}

// literal-constant repetition (all indices are integer-constant expressions)
#define REP4(F, a)  F(a) F((a) + 1) F((a) + 2) F((a) + 3)
#define REP16(F, a) REP4(F, a) REP4(F, (a) + 4) REP4(F, (a) + 8) REP4(F, (a) + 12)
#define REP64(F)    REP16(F, 0) REP16(F, 16) REP16(F, 32) REP16(F, 48)

// ---------------------------------------------------------------------------
// Single fused kernel. 256 blocks (1/batch) x 512 threads (8 waves).
// Phase A: all waves compute me[1024] -> fp32 sMeF + fp16 sMeH.
// Phase B: wave 0 = serial SIR chain, me-tables in REGISTERS (plain local
//          arrays, every access at a literal index -> SROA promotes);
//          waves 1-7 = fp16 fdot2 history dots (conflict-free R5 layout).
// ---------------------------------------------------------------------------
__global__ __launch_bounds__(512, 1) void scan_kernel(
    const float* __restrict__ t,
    const float* __restrict__ y,
    const float* __restrict__ w1, const float* __restrict__ b1,
    const float* __restrict__ w2, const float* __restrict__ b2,
    const float* __restrict__ w3, const float* __restrict__ b3,
    const float* __restrict__ w4, const float* __restrict__ b4,
    const float* __restrict__ beta_p,
    const float* __restrict__ gamma_p,
    float* __restrict__ out)     // [solution (T*B*3) | diff (T*B*3)]
{
    __shared__ __align__(16) float    sMeF[T_N];      // fp32 me (serial tables + fixup)
    __shared__ __align__(16) _Float16 sMeH[T_N];      // fp16 me (dot operand A)
    __shared__ __align__(16) _Float16 sIhR[8 * SIH];  // 8 shifted fp16 I-history rows
    __shared__ float P[2][NDW][64];

    const int b   = blockIdx.x;
    const int tid = threadIdx.x;
    const int wid = tid >> 6;
    const int L   = tid & 63;

    // per-lane dot-geometry constants (chunk-invariant)
    const int f    = (-L) & 7;            // misalignment of lane L's me window
    const int R8   = L + f;               // L rounded up to multiple of 8
    const int row  = L & 7;               // I-history row for this lane
    const int iofs = row * SIH + (f ? 0 : 8);

    // zero the row front-pads (slots representing I[<0])
    if (tid < 64) sIhR[(tid >> 3) * SIH + (tid & 7)] = (_Float16)0.0f;

    // ---- Phase A: me MLP (2 values/thread) ----
#pragma unroll
    for (int v = 0; v < 2; ++v) {
        const int mi = tid + v * 512;
        const float x = t[mi];

        float h1[H_N], h2[H_N];
#pragma unroll
        for (int k = 0; k < H_N; ++k) h1[k] = fast_tanh(fmaf(x, w1[k], b1[k]));

#pragma unroll 4
        for (int k = 0; k < H_N; ++k) {
            float a = b2[k];
#pragma unroll
            for (int j = 0; j < H_N; ++j) a = fmaf(h1[j], w2[j * H_N + k], a);
            h2[k] = fast_tanh(a);
        }

        float a4 = b4[0];
#pragma unroll 4
        for (int k = 0; k < H_N; ++k) {
            float a = b3[k];
#pragma unroll
            for (int j = 0; j < H_N; ++j) a = fmaf(h2[j], w3[j * H_N + k], a);
            a4 = fmaf(fast_tanh(a), w4[k], a4);
        }

        const float meval = fast_sigmoid(a4);
        sMeF[mi] = meval;
        sMeH[mi] = (_Float16)meval;
    }

    // ---- scalars / state ----
    const float dt    = t[0] - t[1];
    const float beta  = beta_p[0];
    const float gma   = gamma_p[0];
    const float invdt = 1.0f / dt;

    const float S0 = y[b * 3 + 0];
    const float I0 = y[b * 3 + 1];
    const float R0 = y[b * 3 + 2];
    const float TOT = S0 + I0 + R0;     // SIR total conserved

    // publish I[0] into all 8 rows
    if (tid < 8) sIhR[tid * SIH + 8 - tid] = (_Float16)I0;

    float* __restrict__ diff = out + (size_t)T_N * B_N * 3;
    if (tid < 3) diff[((size_t)(T_N - 1) * B_N + b) * 3 + tid] = 0.0f;

    __syncthreads();   // sMeF/sMeH/pads/I0 visible

    // fixup me weights (chunk-invariant): mf[d-1] = me[960 - L - d]
    float mf[7];
#pragma unroll
    for (int d = 1; d <= 7; ++d) mf[d - 1] = sMeF[T_N - 64 - L - d];

    const float dtb  = dt * beta;
    const float ndtg = -dt * gma;
    const float dt2  = dt * dt;
    const float meT1 = sMeF[T_N - 1];

    float S = S0, I = I0, oS = S0, oI = I0;
    float acc_cur = 0.0f, acc_nxt = 0.0f, pre = 0.0f;
    float carryS = S0, carryI = I0;

    // register me-tables: plain locals, literal-index init and use only
    float rm[64], rn[64];
    if (wid == 0) {
#define RMINIT(k)                                                       \
        rm[(k)] = ((k) < L) ? sMeF[T_N - L + (k)] : 0.0f;               \
        rn[(k)] = sMeF[T_N - 64 - L + (k)];
        REP64(RMINIT)
#undef RMINIT
    }

    // serial step M_: entering (S,I) = y_{64c+M_-1}; produces y_{64c+M_}.
    // pre was read BEFORE step (M_-1)'s fold -> patch with meT1*I.
    // Longest dependency cycle: I->bI->q->{I',s1->S'} = 3 VALU ops.
#define STEPB(M_, FIRST_)                                               \
    {                                                                   \
        const float sum = (FIRST_) ? pre : fmaf(meT1, I, pre);          \
        float pnx = pre;                                                \
        if ((M_) < 63) pnx = rdlane_i(acc_cur, (M_) + 1);               \
        const float bI = dtb * I;                                       \
        const float i1 = fmaf(ndtg, I, I);                              \
        const float q  = bI * S;                                        \
        const float s1 = S - q;                                         \
        S = fmaf(dt2, sum, s1);                                         \
        I = i1 + q;                                                     \
        const bool cap = (L == (M_));                                   \
        oS = cap ? S : oS;                                              \
        oI = cap ? I : oI;                                              \
        acc_cur = fmaf(rm[(M_)], I, acc_cur);                           \
        acc_nxt = fmaf(rn[(M_)], I, acc_nxt);                           \
        pre = pnx;                                                      \
    }
#define STEP_GE1(M_) if ((M_) >= 1) STEPB(M_, false)
#define STEP_GE2(M_) if ((M_) >= 2) STEPB(M_, false)

    for (int c = 0; c < 16; ++c) {
        if (wid == 0) {
            if (c == 0) {
                // fold initial I0 (t=0 term); lane0's rm[0] is the 0 pad
                acc_cur = rm[0] * I;
                acc_nxt = rn[0] * I;
                pre = rdlane_i(acc_cur, 1);
                STEPB(1, true)
                REP64(STEP_GE2)
            } else {
                float ac = acc_nxt;
#pragma unroll
                for (int w = 0; w < NDW; ++w) ac += P[c & 1][w][L];
                acc_cur = ac;
                acc_nxt = 0.0f;
                pre = rdlane_i(acc_cur, 0);
                STEPB(0, true)
                REP64(STEP_GE1)
            }

            // ---- chunk epilogue (wave 0) ----
            const int j = 64 * c + L;
            const _Float16 hI = (_Float16)oI;
#pragma unroll
            for (int r = 0; r < 8; ++r) sIhR[r * SIH + 8 + (j - r)] = hI;

            const float oR = TOT - oS - oI;
            const size_t so = ((size_t)j * B_N + b) * 3;
            out[so + 0] = oS;
            out[so + 1] = oI;
            out[so + 2] = oR;

            float sm1 = __shfl_up(oS, 1);
            float im1 = __shfl_up(oI, 1);
            if (L == 0) { sm1 = carryS; im1 = carryI; }
            if (j > 0) {
                const float d0 = (oS - sm1) * invdt;
                const float d1 = (oI - im1) * invdt;
                const float d2 = -d0 - d1;
                const size_t dofs = ((size_t)(j - 1) * B_N + b) * 3;
                diff[dofs + 0] = d0;
                diff[dofs + 1] = d1;
                diff[dofs + 2] = d2;
            }
            carryS = rdlane_i(oS, 63);
            carryI = rdlane_i(oI, 63);
        } else if (c < 15) {
            // history dot for chunk c+1 over tau < 64c (R5 layout, unchanged)
            const int w    = wid - 1;
            const int G    = 8 * c;
            const int idx0 = (T_N - 64 * (c + 1)) - R8;
            float p0 = 0.0f, p1 = 0.0f;
            int s = w;
            for (; s + NDW < G; s += 2 * NDW) {
                const h8_t mv0 = *(const h8_t*)&sMeH[idx0 + 8 * s];
                const h8_t iv0 = *(const h8_t*)&sIhR[iofs + 8 * s];
                const h8_t mv1 = *(const h8_t*)&sMeH[idx0 + 8 * (s + NDW)];
                const h8_t iv1 = *(const h8_t*)&sIhR[iofs + 8 * (s + NDW)];
                DOT8(p0, mv0, iv0)
                DOT8(p1, mv1, iv1)
            }
            if (s < G) {
                const h8_t mv0 = *(const h8_t*)&sMeH[idx0 + 8 * s];
                const h8_t iv0 = *(const h8_t*)&sIhR[iofs + 8 * s];
                DOT8(p0, mv0, iv0)
            }
            float p = p0 + p1;
            if (w == 0) {
                // tail fixup: tau = 64c - d, d = 1..f
#pragma unroll
                for (int d = 1; d <= 7; ++d) {
                    const float ih = (float)sIhR[8 + 64 * c - d];   // row 0
                    if (d <= f) p = fmaf(mf[d - 1], ih, p);
                }
            }
            P[(c + 1) & 1][w][L] = p;
        }
        __syncthreads();
    }
#undef STEPB
#undef STEP_GE1
#undef STEP_GE2
}

// ---------------------------------------------------------------------------
// Launcher
// ---------------------------------------------------------------------------
extern "C" void kernel_launch(void* const* d_in, const int* in_sizes, int n_in,
                              void* d_out, int out_size, void* d_ws, size_t ws_size,
                              hipStream_t stream) {
    const float* t     = (const float*)d_in[0];
    const float* y     = (const float*)d_in[1];
    const float* w1    = (const float*)d_in[2];
    const float* b1    = (const float*)d_in[3];
    const float* w2    = (const float*)d_in[4];
    const float* b2    = (const float*)d_in[5];
    const float* w3    = (const float*)d_in[6];
    const float* b3    = (const float*)d_in[7];
    const float* w4    = (const float*)d_in[8];
    const float* b4    = (const float*)d_in[9];
    const float* beta  = (const float*)d_in[10];
    const float* gamma = (const float*)d_in[11];

    scan_kernel<<<B_N, 512, 0, stream>>>(t, y, w1, b1, w2, b2, w3, b3, w4, b4,
                                         beta, gamma, (float*)d_out);
}

// Round 7
// 121.556 us; speedup vs baseline: 2.5356x; 1.0031x over previous
//
#include <hip/hip_runtime.h>

// Problem constants: T=1024, B=256, H=20
#define T_N 1024
#define B_N 256
#define H_N 20
#define NW  8            // waves per block
#define NDW (NW - 1)     // dot waves
#define SIH 1096         // I-history row stride in HALVES (conflict-free layout, see R5)

typedef _Float16 h8_t __attribute__((ext_vector_type(8)));

#if __has_builtin(__builtin_amdgcn_fdot2)
#define DOT8(acc, mv, iv)                                                           \
    acc = __builtin_amdgcn_fdot2(__builtin_shufflevector(mv, mv, 0, 1),             \
                                 __builtin_shufflevector(iv, iv, 0, 1), acc, false);\
    acc = __builtin_amdgcn_fdot2(__builtin_shufflevector(mv, mv, 2, 3),             \
                                 __builtin_shufflevector(iv, iv, 2, 3), acc, false);\
    acc = __builtin_amdgcn_fdot2(__builtin_shufflevector(mv, mv, 4, 5),             \
                                 __builtin_shufflevector(iv, iv, 4, 5), acc, false);\
    acc = __builtin_amdgcn_fdot2(__builtin_shufflevector(mv, mv, 6, 7),             \
                                 __builtin_shufflevector(iv, iv, 6, 7), acc, false);
#else
#define DOT8(acc, mv, iv)                                                           \
    _Pragma("unroll")                                                               \
    for (int _k = 0; _k < 8; ++_k) acc = fmaf((float)mv[_k], (float)iv[_k], acc);
#endif

__device__ __forceinline__ float rdlane_i(float v, int lane) {
    return __uint_as_float((unsigned)__builtin_amdgcn_readlane((int)__float_as_uint(v), lane));
}
__device__ __forceinline__ float fast_tanh(float x) {
    const float e = __expf(2.0f * x);
    return fmaf(-2.0f, __builtin_amdgcn_rcpf(e + 1.0f), 1.0f);
}
__device__ __forceinline__ float fast_sigmoid(float x) {
    return __builtin_amdgcn_rcpf(1.0f + __expf(-x));
}

// explicit literal-token repetition (tokens must be plain literals for ##)
#define REP64(F) \
    F(0) F(1) F(2) F(3) F(4) F(5) F(6) F(7) F(8) F(9) F(10) F(11) F(12) F(13) \
    F(14) F(15) F(16) F(17) F(18) F(19) F(20) F(21) F(22) F(23) F(24) F(25)   \
    F(26) F(27) F(28) F(29) F(30) F(31) F(32) F(33) F(34) F(35) F(36) F(37)   \
    F(38) F(39) F(40) F(41) F(42) F(43) F(44) F(45) F(46) F(47) F(48) F(49)   \
    F(50) F(51) F(52) F(53) F(54) F(55) F(56) F(57) F(58) F(59) F(60) F(61)   \
    F(62) F(63)

// ---------------------------------------------------------------------------
// Single fused kernel. 256 blocks (1/batch) x 512 threads (8 waves).
// Phase A: all waves compute me[1024] -> fp32 sMeF + fp16 sMeH.
// Phase B: wave 0 = serial SIR chain with me-tables held in 128 NAMED scalar
//          variables (no alloca -> guaranteed VGPRs, no SROA dependence);
//          waves 1-7 = fp16 fdot2 history dots (conflict-free R5 layout).
// ---------------------------------------------------------------------------
__global__ __launch_bounds__(512, 1) void scan_kernel(
    const float* __restrict__ t,
    const float* __restrict__ y,
    const float* __restrict__ w1, const float* __restrict__ b1,
    const float* __restrict__ w2, const float* __restrict__ b2,
    const float* __restrict__ w3, const float* __restrict__ b3,
    const float* __restrict__ w4, const float* __restrict__ b4,
    const float* __restrict__ beta_p,
    const float* __restrict__ gamma_p,
    float* __restrict__ out)     // [solution (T*B*3) | diff (T*B*3)]
{
    __shared__ __align__(16) float    sMeF[T_N];      // fp32 me (serial tables + fixup)
    __shared__ __align__(16) _Float16 sMeH[T_N];      // fp16 me (dot operand A)
    __shared__ __align__(16) _Float16 sIhR[8 * SIH];  // 8 shifted fp16 I-history rows
    __shared__ float P[2][NDW][64];

    const int b   = blockIdx.x;
    const int tid = threadIdx.x;
    const int wid = tid >> 6;
    const int L   = tid & 63;

    // per-lane dot-geometry constants (chunk-invariant)
    const int f    = (-L) & 7;            // misalignment of lane L's me window
    const int R8   = L + f;               // L rounded up to multiple of 8
    const int row  = L & 7;               // I-history row for this lane
    const int iofs = row * SIH + (f ? 0 : 8);

    // zero the row front-pads (slots representing I[<0])
    if (tid < 64) sIhR[(tid >> 3) * SIH + (tid & 7)] = (_Float16)0.0f;

    // ---- Phase A: me MLP (2 values/thread) ----
#pragma unroll
    for (int v = 0; v < 2; ++v) {
        const int mi = tid + v * 512;
        const float x = t[mi];

        float h1[H_N], h2[H_N];
#pragma unroll
        for (int k = 0; k < H_N; ++k) h1[k] = fast_tanh(fmaf(x, w1[k], b1[k]));

#pragma unroll 4
        for (int k = 0; k < H_N; ++k) {
            float a = b2[k];
#pragma unroll
            for (int j = 0; j < H_N; ++j) a = fmaf(h1[j], w2[j * H_N + k], a);
            h2[k] = fast_tanh(a);
        }

        float a4 = b4[0];
#pragma unroll 4
        for (int k = 0; k < H_N; ++k) {
            float a = b3[k];
#pragma unroll
            for (int j = 0; j < H_N; ++j) a = fmaf(h2[j], w3[j * H_N + k], a);
            a4 = fmaf(fast_tanh(a), w4[k], a4);
        }

        const float meval = fast_sigmoid(a4);
        sMeF[mi] = meval;
        sMeH[mi] = (_Float16)meval;
    }

    // ---- scalars / state ----
    const float dt    = t[0] - t[1];
    const float beta  = beta_p[0];
    const float gma   = gamma_p[0];
    const float invdt = 1.0f / dt;

    const float S0 = y[b * 3 + 0];
    const float I0 = y[b * 3 + 1];
    const float R0 = y[b * 3 + 2];
    const float TOT = S0 + I0 + R0;     // SIR total conserved

    // publish I[0] into all 8 rows
    if (tid < 8) sIhR[tid * SIH + 8 - tid] = (_Float16)I0;

    float* __restrict__ diff = out + (size_t)T_N * B_N * 3;
    if (tid < 3) diff[((size_t)(T_N - 1) * B_N + b) * 3 + tid] = 0.0f;

    __syncthreads();   // sMeF/sMeH/pads/I0 visible

    // fixup me weights (chunk-invariant): mf[d-1] = me[960 - L - d]
    float mf[7];
#pragma unroll
    for (int d = 1; d <= 7; ++d) mf[d - 1] = sMeF[T_N - 64 - L - d];

    const float dtb  = dt * beta;
    const float ndtg = -dt * gma;
    const float dt2  = dt * dt;
    const float meT1 = sMeF[T_N - 1];

    float S = S0, I = I0, oS = S0, oI = I0;
    float acc_cur = 0.0f, acc_nxt = 0.0f, pre = 0.0f;
    float carryS = S0, carryI = I0;

    // register me-tables: 128 NAMED scalars (no array, no alloca, no SROA)
#define TBLDECL(k) float rm_##k, rn_##k;
    REP64(TBLDECL)
#undef TBLDECL
    if (wid == 0) {
#define TBLINIT(k)                                                      \
        rm_##k = ((k) < L) ? sMeF[T_N - L + (k)] : 0.0f;                \
        rn_##k = sMeF[T_N - 64 - L + (k)];
        REP64(TBLINIT)
#undef TBLINIT
    }

    // serial step M_: entering (S,I) = y_{64c+M_-1}; produces y_{64c+M_}.
    // pre was read BEFORE step (M_-1)'s fold -> patch with meT1*I.
    // Longest dependency cycle: I->bI->q->{I',s1->S'} = 3 VALU ops.
#define STEPB(M_, FIRST_)                                               \
    {                                                                   \
        const float sum = (FIRST_) ? pre : fmaf(meT1, I, pre);          \
        float pnx = pre;                                                \
        if ((M_) < 63) pnx = rdlane_i(acc_cur, (M_) + 1);               \
        const float bI = dtb * I;                                       \
        const float i1 = fmaf(ndtg, I, I);                              \
        const float q  = bI * S;                                        \
        const float s1 = S - q;                                         \
        S = fmaf(dt2, sum, s1);                                         \
        I = i1 + q;                                                     \
        const bool cap = (L == (M_));                                   \
        oS = cap ? S : oS;                                              \
        oI = cap ? I : oI;                                              \
        acc_cur = fmaf(rm_##M_, I, acc_cur);                            \
        acc_nxt = fmaf(rn_##M_, I, acc_nxt);                            \
        pre = pnx;                                                      \
    }
#define STEP_GE1(M_) if ((M_) >= 1) STEPB(M_, false)
#define STEP_GE2(M_) if ((M_) >= 2) STEPB(M_, false)

    for (int c = 0; c < 16; ++c) {
        if (wid == 0) {
            if (c == 0) {
                // fold initial I0 (t=0 term); lane0's rm_0 is the 0 pad
                acc_cur = rm_0 * I;
                acc_nxt = rn_0 * I;
                pre = rdlane_i(acc_cur, 1);
                STEPB(1, true)
                REP64(STEP_GE2)
            } else {
                float ac = acc_nxt;
#pragma unroll
                for (int w = 0; w < NDW; ++w) ac += P[c & 1][w][L];
                acc_cur = ac;
                acc_nxt = 0.0f;
                pre = rdlane_i(acc_cur, 0);
                STEPB(0, true)
                REP64(STEP_GE1)
            }

            // ---- chunk epilogue (wave 0) ----
            const int j = 64 * c + L;
            const _Float16 hI = (_Float16)oI;
#pragma unroll
            for (int r = 0; r < 8; ++r) sIhR[r * SIH + 8 + (j - r)] = hI;

            const float oR = TOT - oS - oI;
            const size_t so = ((size_t)j * B_N + b) * 3;
            out[so + 0] = oS;
            out[so + 1] = oI;
            out[so + 2] = oR;

            float sm1 = __shfl_up(oS, 1);
            float im1 = __shfl_up(oI, 1);
            if (L == 0) { sm1 = carryS; im1 = carryI; }
            if (j > 0) {
                const float d0 = (oS - sm1) * invdt;
                const float d1 = (oI - im1) * invdt;
                const float d2 = -d0 - d1;
                const size_t dofs = ((size_t)(j - 1) * B_N + b) * 3;
                diff[dofs + 0] = d0;
                diff[dofs + 1] = d1;
                diff[dofs + 2] = d2;
            }
            carryS = rdlane_i(oS, 63);
            carryI = rdlane_i(oI, 63);
        } else if (c < 15) {
            // history dot for chunk c+1 over tau < 64c (R5 layout, unchanged)
            const int w    = wid - 1;
            const int G    = 8 * c;
            const int idx0 = (T_N - 64 * (c + 1)) - R8;
            float p0 = 0.0f, p1 = 0.0f;
            int s = w;
            for (; s + NDW < G; s += 2 * NDW) {
                const h8_t mv0 = *(const h8_t*)&sMeH[idx0 + 8 * s];
                const h8_t iv0 = *(const h8_t*)&sIhR[iofs + 8 * s];
                const h8_t mv1 = *(const h8_t*)&sMeH[idx0 + 8 * (s + NDW)];
                const h8_t iv1 = *(const h8_t*)&sIhR[iofs + 8 * (s + NDW)];
                DOT8(p0, mv0, iv0)
                DOT8(p1, mv1, iv1)
            }
            if (s < G) {
                const h8_t mv0 = *(const h8_t*)&sMeH[idx0 + 8 * s];
                const h8_t iv0 = *(const h8_t*)&sIhR[iofs + 8 * s];
                DOT8(p0, mv0, iv0)
            }
            float p = p0 + p1;
            if (w == 0) {
                // tail fixup: tau = 64c - d, d = 1..f
#pragma unroll
                for (int d = 1; d <= 7; ++d) {
                    const float ih = (float)sIhR[8 + 64 * c - d];   // row 0
                    if (d <= f) p = fmaf(mf[d - 1], ih, p);
                }
            }
            P[(c + 1) & 1][w][L] = p;
        }
        __syncthreads();
    }
#undef STEPB
#undef STEP_GE1
#undef STEP_GE2
}

// ---------------------------------------------------------------------------
// Launcher
// ---------------------------------------------------------------------------
extern "C" void kernel_launch(void* const* d_in, const int* in_sizes, int n_in,
                              void* d_out, int out_size, void* d_ws, size_t ws_size,
                              hipStream_t stream) {
    const float* t     = (const float*)d_in[0];
    const float* y     = (const float*)d_in[1];
    const float* w1    = (const float*)d_in[2];
    const float* b1    = (const float*)d_in[3];
    const float* w2    = (const float*)d_in[4];
    const float* b2    = (const float*)d_in[5];
    const float* w3    = (const float*)d_in[6];
    const float* b3    = (const float*)d_in[7];
    const float* w4    = (const float*)d_in[8];
    const float* b4    = (const float*)d_in[9];
    const float* beta  = (const float*)d_in[10];
    const float* gamma = (const float*)d_in[11];

    scan_kernel<<<B_N, 512, 0, stream>>>(t, y, w1, b1, w2, b2, w3, b3, w4, b4,
                                         beta, gamma, (float*)d_out);
}